// Round 1
// baseline (315.762 us; speedup 1.0000x reference)
//
#include <hip/hip_runtime.h>
#include <hip/hip_bf16.h>

namespace {

constexpr int kB = 256;
constexpr int kS = 512;
constexpr int kJ = 22;
constexpr int kC = 6;
constexpr int CHUNK = 62;                       // useful frames per 64-lane wave (2 overlap)
constexpr int NCHUNK = (kS + CHUNK - 1) / CHUNK; // 9

__device__ constexpr int PAR[kJ] =
    {-1, 0, 1, 2, 3, 4, 3, 6, 7, 8, 3, 10, 11, 12, 1, 14, 15, 16, 17, 1, 19, 20};

// cont6d_to_mat: columns of R are b1, b2, b3 (matches jnp.stack(..., axis=-1))
__device__ __forceinline__ void cont6d_to_mat(const float a[6], float R[3][3]) {
    float n1 = sqrtf(a[0]*a[0] + a[1]*a[1] + a[2]*a[2]);
    n1 = fmaxf(n1, 1e-12f);
    float i1 = 1.0f / n1;
    float b1x = a[0]*i1, b1y = a[1]*i1, b1z = a[2]*i1;
    float dp = b1x*a[3] + b1y*a[4] + b1z*a[5];
    float ux = a[3] - b1x*dp, uy = a[4] - b1y*dp, uz = a[5] - b1z*dp;
    float n2 = sqrtf(ux*ux + uy*uy + uz*uz);
    n2 = fmaxf(n2, 1e-12f);
    float i2 = 1.0f / n2;
    float b2x = ux*i2, b2y = uy*i2, b2z = uz*i2;
    float b3x = b1y*b2z - b1z*b2y;
    float b3y = b1z*b2x - b1x*b2z;
    float b3z = b1x*b2y - b1y*b2x;
    R[0][0] = b1x; R[1][0] = b1y; R[2][0] = b1z;
    R[0][1] = b2x; R[1][1] = b2y; R[2][1] = b2z;
    R[0][2] = b3x; R[1][2] = b3y; R[2][2] = b3z;
}

__global__ __launch_bounds__(64)
void motion_loss_kernel(const float* __restrict__ pred,
                        const float* __restrict__ targ,
                        const float* __restrict__ offs,
                        float* __restrict__ acc /* 9 fp32 accumulators */) {
    const int lane  = threadIdx.x;            // 0..63
    const int bid   = blockIdx.x;             // b * NCHUNK + chunk
    const int b     = bid / NCHUNK;
    const int chunk = bid - b * NCHUNK;
    const int s     = chunk * CHUNK + lane;

    const bool valid = (s < kS);
    const int  sc    = valid ? s : (kS - 1);   // clamp: loads stay in-bounds & finite
    // weights: per-frame losses only from lanes < CHUNK (overlap lanes 62/63 are
    // recomputed as lanes 0/1 of the next chunk); vel needs s+1, acc needs s+2.
    const float wf = (valid && lane < CHUNK)       ? 1.f : 0.f;
    const float wv = (lane < CHUNK && s + 1 < kS)  ? 1.f : 0.f;
    const float wa = (lane < CHUNK && s + 2 < kS)  ? 1.f : 0.f;

    const size_t fbase = ((size_t)b * kS + (size_t)sc) * (kJ * kC);
    const float* pf = pred + fbase;
    const float* tf = targ + fbase;

    float sr1 = 0.f, sr2 = 0.f, srot = 0.f, spos = 0.f, svel = 0.f,
          ssmo = 0.f, sflo = 0.f, scon = 0.f, stil = 0.f;

    // global rotations / positions (SROA'd to registers under full unroll)
    float gRp[kJ][3][3], gRt[kJ][3][3];
    float pP[kJ][3], pT[kJ][3];
    #pragma unroll
    for (int r = 0; r < 3; ++r) {
        #pragma unroll
        for (int c = 0; c < 3; ++c) {
            gRp[0][r][c] = (r == c) ? 1.f : 0.f;
            gRt[0][r][c] = (r == c) ? 1.f : 0.f;
        }
        pP[0][r] = 0.f; pT[0][r] = 0.f;
    }

    { // root loss part 1: joint 0, channels 0..2
        const float2* qp = reinterpret_cast<const float2*>(pf);
        const float2* qt = reinterpret_cast<const float2*>(tf);
        float2 p01 = qp[0], t01 = qt[0];
        float  p2  = pf[2], t2  = tf[2];
        float d0 = p01.x - t01.x, d1 = p01.y - t01.y, d2 = p2 - t2;
        sr1 += wf * (d0*d0 + d1*d1 + d2*d2);
    }

    #pragma unroll
    for (int i = 1; i < kJ; ++i) {
        const int p = PAR[i];

        float a[6], g[6];
        {
            const float2* qp = reinterpret_cast<const float2*>(pf + i * 6);
            const float2* qt = reinterpret_cast<const float2*>(tf + i * 6);
            float2 a0 = qp[0], a1 = qp[1], a2 = qp[2];
            float2 g0 = qt[0], g1 = qt[1], g2 = qt[2];
            a[0]=a0.x; a[1]=a0.y; a[2]=a1.x; a[3]=a1.y; a[4]=a2.x; a[5]=a2.y;
            g[0]=g0.x; g[1]=g0.y; g[2]=g1.x; g[3]=g1.y; g[4]=g2.x; g[5]=g2.y;
        }

        // raw-channel losses
        float dsum = 0.f;
        #pragma unroll
        for (int k = 0; k < 6; ++k) { float d = a[k] - g[k]; dsum += d * d; }
        if (i == 1) sr2 += wf * dsum; else srot += wf * dsum;

        float Rp[3][3], Rt[3][3];
        cont6d_to_mat(a, Rp);
        cont6d_to_mat(g, Rt);

        if (i == 2) { // tilt: column 1 (b2) of spine local rotation
            float d0 = Rp[0][1] - Rt[0][1];
            float d1 = Rp[1][1] - Rt[1][1];
            float d2 = Rp[2][1] - Rt[2][1];
            stil += wf * (d0*d0 + d1*d1 + d2*d2);
        }

        // FK: gR[i] = gR[p] @ R;  pos[i] = pos[p] + gR[p] @ off[i]
        const float ox = offs[i*3+0], oy = offs[i*3+1], oz = offs[i*3+2];
        #pragma unroll
        for (int r = 0; r < 3; ++r) {
            #pragma unroll
            for (int c = 0; c < 3; ++c) {
                gRp[i][r][c] = gRp[p][r][0]*Rp[0][c] + gRp[p][r][1]*Rp[1][c] + gRp[p][r][2]*Rp[2][c];
                gRt[i][r][c] = gRt[p][r][0]*Rt[0][c] + gRt[p][r][1]*Rt[1][c] + gRt[p][r][2]*Rt[2][c];
            }
            pP[i][r] = pP[p][r] + gRp[p][r][0]*ox + gRp[p][r][1]*oy + gRp[p][r][2]*oz;
            pT[i][r] = pT[p][r] + gRt[p][r][0]*ox + gRt[p][r][1]*oy + gRt[p][r][2]*oz;
        }

        // position diff + pos/vel/smooth losses via in-wave shuffles
        float dx = pP[i][0] - pT[i][0];
        float dy = pP[i][1] - pT[i][1];
        float dz = pP[i][2] - pT[i][2];
        spos += wf * (dx*dx + dy*dy + dz*dz);

        float dx1 = __shfl_down(dx, 1), dy1 = __shfl_down(dy, 1), dz1 = __shfl_down(dz, 1);
        float dx2 = __shfl_down(dx, 2), dy2 = __shfl_down(dy, 2), dz2 = __shfl_down(dz, 2);
        float vx = dx1 - dx, vy = dy1 - dy, vz = dz1 - dz;
        svel += wv * (vx*vx + vy*vy + vz*vz);
        float ax = dx2 - 2.f*dx1 + dx;
        float ay = dy2 - 2.f*dy1 + dy;
        float az = dz2 - 2.f*dz1 + dz;
        ssmo += wa * (ax*ax + ay*ay + az*az);

        if (i == 18 || i == 21) { // feet: floor + contact
            sflo += wf * (dy * dy);
            float tx = pT[i][0], ty = pT[i][1], tz = pT[i][2];
            float tx1 = __shfl_down(tx, 1), ty1 = __shfl_down(ty, 1), tz1 = __shfl_down(tz, 1);
            float gvx = tx1 - tx, gvy = ty1 - ty, gvz = tz1 - tz;
            float gn2 = gvx*gvx + gvy*gvy + gvz*gvz;
            // pred_feet_vel = gt_feet_vel + (d[s+1]-d[s])
            float pvx = gvx + vx, pvy = gvy + vy, pvz = gvz + vz;
            float pn = sqrtf(pvx*pvx + pvy*pvy + pvz*pvz);
            float planted = (gn2 < 0.005f * 0.005f) ? 1.f : 0.f;
            scon += wv * pn * planted;
        }
    }

    // wave butterfly reduce, then one atomicAdd per sum from lane 0
    float vals[9] = {sr1, sr2, srot, spos, svel, ssmo, sflo, scon, stil};
    #pragma unroll
    for (int k = 0; k < 9; ++k) {
        float v = vals[k];
        #pragma unroll
        for (int o = 32; o > 0; o >>= 1) v += __shfl_xor(v, o);
        if (lane == 0) atomicAdd(&acc[k], v);
    }
}

__global__ void finalize_kernel(const float* __restrict__ acc, float* __restrict__ out) {
    const float BS    = (float)kB * (float)kS;       // 131072
    const float c_r1  = BS * 3.f;
    const float c_r2  = BS * 6.f;
    const float c_rot = BS * 120.f;                  // 20 joints * 6 ch
    const float c_pos = BS * 66.f;                   // 22 joints * 3
    const float c_vel = (float)kB * (float)(kS - 1) * 66.f;
    const float c_smo = (float)kB * (float)(kS - 2) * 66.f;
    const float c_flo = BS * 2.f;
    const float c_con = (float)kB * (float)(kS - 1) * 2.f;
    const float c_til = BS * 3.f;
    float total = 5.0f * (acc[0] / c_r1 + acc[1] / c_r2)
                + 1.0f * (acc[2] / c_rot)
                + 2.0f * (acc[3] / c_pos)
                + 1.0f * (acc[4] / c_vel)
                + 0.5f * (acc[5] / c_smo)
                + 2.0f * (acc[6] / c_flo)
                + 2.0f * (acc[7] / c_con)
                + 1.0f * (acc[8] / c_til);
    out[0] = total;
}

} // namespace

extern "C" void kernel_launch(void* const* d_in, const int* in_sizes, int n_in,
                              void* d_out, int out_size, void* d_ws, size_t ws_size,
                              hipStream_t stream) {
    const float* pred = (const float*)d_in[0];
    const float* targ = (const float*)d_in[1];
    const float* offs = (const float*)d_in[2];
    float* acc = (float*)d_ws;

    hipMemsetAsync(acc, 0, 9 * sizeof(float), stream);
    motion_loss_kernel<<<dim3(kB * NCHUNK), dim3(64), 0, stream>>>(pred, targ, offs, acc);
    finalize_kernel<<<1, 1, 0, stream>>>(acc, (float*)d_out);
}